// Round 21
// baseline (147.669 us; speedup 1.0000x reference)
//
#include <hip/hip_runtime.h>
#include <hip/hip_bf16.h>
#include <hip/hip_cooperative_groups.h>
#include <math.h>

namespace cg = cooperative_groups;

#define B_   32
#define D_   128
#define L_   512
#define NH_  8
#define DK_  16

#define QKS  24    // Qh/Kh row stride in f16 ([512][16] + pad 8): 48B rows, 16B-aligned
#define VST  520   // V row stride ([16][512] + pad 8)
#define XST  40    // x-stage row stride ([512][32] + pad 8), XOR-swizzled banks
#define ETS  20    // epilogue tile row stride in f16 ([64][16] + pad 4)

#define LOG2E 1.4426950408889634f
#define QSC   (0.25f * LOG2E)          // fold 1/sqrt(dk) * log2(e) into Q
#define SH2   (-11.541560327111707f)   // -8 * log2(e): softmax shift, in MFMA acc

typedef _Float16 h2 __attribute__((ext_vector_type(2)));
typedef _Float16 h4 __attribute__((ext_vector_type(4)));
typedef _Float16 h8 __attribute__((ext_vector_type(8)));
typedef __attribute__((ext_vector_type(4)))  float f32x4;
typedef __attribute__((ext_vector_type(16))) float f32x16;
typedef unsigned int u32x2 __attribute__((ext_vector_type(2)));
typedef unsigned int u32x4 __attribute__((ext_vector_type(4)));

__device__ __forceinline__ unsigned int cvt_pk_u(float a, float b) {
    return __builtin_bit_cast(unsigned int, __builtin_amdgcn_cvt_pkrtz(a, b));
}

#define MFMA_K32(a, b, c) __builtin_amdgcn_mfma_f32_16x16x32_f16((a), (b), (c), 0, 0, 0)
#define MFMA_32(a, b, c)  __builtin_amdgcn_mfma_f32_32x32x16_f16((a), (b), (c), 0, 0, 0)

// ---------------------------------------------------------------------------
// Fused cooperative kernel: Phase A = attention (R20 champion, unchanged
// numerics), threadfence + grid.sync, Phase B = out_proj (R20 body, 2
// tasks per 512-thr block). 256 blocks x 512 thr = 1 block/CU (co-resident).
// ---------------------------------------------------------------------------
__global__ __launch_bounds__(512, 2) void attn_fused_coop(
    const float* __restrict__ x,      // [B][D][L] fp32
    const float* __restrict__ Wq,     // [NH][B][DK][D]
    const float* __restrict__ Wk,
    const float* __restrict__ Wv,
    const float* __restrict__ Wo,     // [B][128][128]
    _Float16* __restrict__ Ht,        // [B][8][512][16] fp16 head-major
    float* __restrict__ out)          // [B][128][512]
{
    __shared__ __attribute__((aligned(16))) unsigned char SMEM[2 * 512 * XST * 2]; // 80 KB
    __shared__ __attribute__((aligned(16))) _Float16 Qh[512 * QKS];   // 24.6 KB
    __shared__ __attribute__((aligned(16))) _Float16 Kh[512 * QKS];   // 24.6 KB
    __shared__ __attribute__((aligned(16))) _Float16 Vs[16 * VST];    // 16.6 KB

    _Float16* T32a = (_Float16*)SMEM;
    _Float16* T32b = T32a + 512 * XST;

    const int nb = blockIdx.x;
    const int n  = nb >> 5;
    const int b  = nb & 31;
    const int t  = threadIdx.x;
    const int wv = t >> 6;          // wave 0..7
    const int ln = t & 63;
    const int l16 = ln & 15;
    const int g4  = ln >> 4;        // 0..3
    const int lm  = ln & 31;        // 32-tile row/col index
    const int hi  = ln >> 5;        // 0..1

    const float* xb = x + (size_t)b * D_ * L_;
    const size_t woff = (size_t)(n * B_ + b) * DK_ * D_;
    const float* pWq = Wq + woff;
    const float* pWk = Wk + woff;
    const float* pWv = Wv + woff;

    // staging assignment: thread t handles d-octet sdd, l-quad sl0
    const int sdd  = (t >> 7) * 8;         // 0,8,16,24 (local d base)
    const int sl0  = (t & 127) * 4;        // l base 0..508
    const int sxor = ((t & 127) & 3) << 3; // bank swizzle

    #define STAGE(ks_, buf_)                                                   \
    {                                                                          \
        f32x4 xv[8];                                                           \
        _Pragma("unroll")                                                      \
        for (int j = 0; j < 8; ++j)                                            \
            xv[j] = *(const f32x4*)&xb[(size_t)((ks_) * 32 + sdd + j) * L_ + sl0]; \
        _Pragma("unroll")                                                      \
        for (int i = 0; i < 4; ++i) {                                          \
            h8 w;                                                              \
            _Pragma("unroll")                                                  \
            for (int j = 0; j < 8; ++j) w[j] = (_Float16)xv[j][i];             \
            *(h8*)&(buf_)[(sl0 + i) * XST + (sdd ^ sxor)] = w;                 \
        }                                                                      \
    }

    // ================= P1: Q,K,V = W @ x  (fp16 16x16x32 MFMA) ============
    f32x4 Qa[4], Ka[4], Va[4];
    #pragma unroll
    for (int lt = 0; lt < 4; ++lt) {
        Qa[lt] = (f32x4){0.f,0.f,0.f,0.f};
        Ka[lt] = (f32x4){0.f,0.f,0.f,0.f};
        Va[lt] = (f32x4){0.f,0.f,0.f,0.f};
    }

    STAGE(0, T32a);
    __syncthreads();

    #pragma unroll
    for (int ks = 0; ks < 4; ++ks) {
        _Float16* cur = (ks & 1) ? T32b : T32a;
        _Float16* nxt = (ks & 1) ? T32a : T32b;
        if (ks < 3) STAGE(ks + 1, nxt);     // loads issue before compute(ks)

        const int d0 = ks * 32 + g4 * 8;    // A/B-frag k = 8*g4 + j
        const float* aq = pWq + l16 * D_ + d0;
        const float* ak = pWk + l16 * D_ + d0;
        const float* av = pWv + l16 * D_ + d0;
        const f32x4 q0 = *(const f32x4*)aq, q1 = *(const f32x4*)(aq + 4);
        const f32x4 k0 = *(const f32x4*)ak, k1 = *(const f32x4*)(ak + 4);
        const f32x4 v0 = *(const f32x4*)av, v1 = *(const f32x4*)(av + 4);
        h8 Aq, Ak, Av;
        #pragma unroll
        for (int j = 0; j < 4; ++j) {
            Aq[j] = (_Float16)q0[j]; Aq[j + 4] = (_Float16)q1[j];
            Ak[j] = (_Float16)k0[j]; Ak[j + 4] = (_Float16)k1[j];
            Av[j] = (_Float16)v0[j]; Av[j + 4] = (_Float16)v1[j];
        }
        #pragma unroll
        for (int lt = 0; lt < 4; ++lt) {
            const int l = wv * 64 + lt * 16 + l16;
            const h8 Bx = *(const h8*)&cur[l * XST + ((g4 * 8) ^ ((((l) >> 2) & 3) << 3))];
            Qa[lt] = MFMA_K32(Aq, Bx, Qa[lt]);
            Ka[lt] = MFMA_K32(Ak, Bx, Ka[lt]);
            Va[lt] = MFMA_K32(Av, Bx, Va[lt]);
        }
        __syncthreads();
    }

    // Q^T (pre-scaled), K^T, V -> LDS.
    #pragma unroll
    for (int lt = 0; lt < 4; ++lt) {
        const int l = wv * 64 + lt * 16 + l16;
        h4 qv, kv;
        #pragma unroll
        for (int r = 0; r < 4; ++r) {
            qv[r] = (_Float16)(Qa[lt][r] * QSC);
            kv[r] = (_Float16)Ka[lt][r];
            Vs[(g4 * 4 + r) * VST + l] = (_Float16)Va[lt][r];
        }
        *(h4*)&Qh[l * QKS + g4 * 4] = qv;
        *(h4*)&Kh[l * QKS + g4 * 4] = kv;
    }
    __syncthreads();   // T32a/b dead -> reusable by epilogue

    // ====== P2: 2 x 32-m-tiles per wave, shared B-side reads, free Z ======
    const int m0 = wv * 64;
    const h8 Bk0 = *(const h8*)&Kh[(m0 + lm) * QKS + 8 * hi];
    const h8 Bk1 = *(const h8*)&Kh[(m0 + 32 + lm) * QKS + 8 * hi];

    f32x16 shiftacc, pv0, pv1;
    #pragma unroll
    for (int i = 0; i < 16; ++i) { shiftacc[i] = SH2; pv0[i] = 0.f; pv1[i] = 0.f; }

    const bool vsel = (lm < 16);
    const int  vrow = lm & 15;
    const h8 ones8 = {(_Float16)1.f,(_Float16)1.f,(_Float16)1.f,(_Float16)1.f,
                      (_Float16)1.f,(_Float16)1.f,(_Float16)1.f,(_Float16)1.f};

    #pragma unroll 2
    for (int t32 = 0; t32 < 16; ++t32) {
        const int lb = t32 * 32;
        const h8 Aq2  = *(const h8*)&Qh[(lb + lm) * QKS + 8 * hi];
        const h8 Bv1r = *(const h8*)&Vs[vrow * VST + lb + 8 * hi];
        const h8 Bv2r = *(const h8*)&Vs[vrow * VST + lb + 16 + 8 * hi];
        const h8 Bv1 = vsel ? Bv1r : ones8;
        const h8 Bv2 = vsel ? Bv2r : ones8;

        const f32x16 sc0 = MFMA_32(Aq2, Bk0, shiftacc);  // pre-shifted scores
        const f32x16 sc1 = MFMA_32(Aq2, Bk1, shiftacc);

        float pA[16], pB[16];
        #pragma unroll
        for (int r = 0; r < 16; ++r) pA[r] = __builtin_amdgcn_exp2f(sc0[r]);
        #pragma unroll
        for (int r = 0; r < 16; ++r) pB[r] = __builtin_amdgcn_exp2f(sc1[r]);

        const unsigned int a0 = cvt_pk_u(pA[0],  pA[1]);
        const unsigned int a1 = cvt_pk_u(pA[2],  pA[3]);
        const unsigned int a2 = cvt_pk_u(pA[4],  pA[5]);
        const unsigned int a3 = cvt_pk_u(pA[6],  pA[7]);
        const unsigned int a4 = cvt_pk_u(pA[8],  pA[9]);
        const unsigned int a5 = cvt_pk_u(pA[10], pA[11]);
        const unsigned int a6 = cvt_pk_u(pA[12], pA[13]);
        const unsigned int a7 = cvt_pk_u(pA[14], pA[15]);
        const unsigned int b0 = cvt_pk_u(pB[0],  pB[1]);
        const unsigned int b1 = cvt_pk_u(pB[2],  pB[3]);
        const unsigned int b2 = cvt_pk_u(pB[4],  pB[5]);
        const unsigned int b3 = cvt_pk_u(pB[6],  pB[7]);
        const unsigned int b4 = cvt_pk_u(pB[8],  pB[9]);
        const unsigned int b5 = cvt_pk_u(pB[10], pB[11]);
        const unsigned int b6 = cvt_pk_u(pB[12], pB[13]);
        const unsigned int b7 = cvt_pk_u(pB[14], pB[15]);

        const u32x2 sA02 = __builtin_amdgcn_permlane32_swap(a0, a2, false, false);
        const u32x2 sA13 = __builtin_amdgcn_permlane32_swap(a1, a3, false, false);
        const u32x2 sA46 = __builtin_amdgcn_permlane32_swap(a4, a6, false, false);
        const u32x2 sA57 = __builtin_amdgcn_permlane32_swap(a5, a7, false, false);
        const u32x2 sB02 = __builtin_amdgcn_permlane32_swap(b0, b2, false, false);
        const u32x2 sB13 = __builtin_amdgcn_permlane32_swap(b1, b3, false, false);
        const u32x2 sB46 = __builtin_amdgcn_permlane32_swap(b4, b6, false, false);
        const u32x2 sB57 = __builtin_amdgcn_permlane32_swap(b5, b7, false, false);
        const h8 A1m0 = __builtin_bit_cast(h8, (u32x4){sA02.x, sA13.x, sA02.y, sA13.y});
        const h8 A2m0 = __builtin_bit_cast(h8, (u32x4){sA46.x, sA57.x, sA46.y, sA57.y});
        const h8 A1m1 = __builtin_bit_cast(h8, (u32x4){sB02.x, sB13.x, sB02.y, sB13.y});
        const h8 A2m1 = __builtin_bit_cast(h8, (u32x4){sB46.x, sB57.x, sB46.y, sB57.y});

        pv0 = MFMA_32(A1m0, Bv1, pv0);
        pv0 = MFMA_32(A2m0, Bv2, pv0);
        pv1 = MFMA_32(A1m1, Bv1, pv1);
        pv1 = MFMA_32(A2m1, Bv2, pv1);
    }

    // ====== epilogue: normalize -> per-wave LDS tile -> coalesced store ===
    _Float16* ET = ((_Float16*)SMEM) + wv * 64 * ETS;
    const int zlane = 16 + 32 * hi;
    #pragma unroll
    for (int r = 0; r < 16; ++r) {
        const int mrow = (r & 3) + 8 * (r >> 2) + 4 * hi;
        const float zr0 = __shfl(pv0[r], zlane);
        const float zr1 = __shfl(pv1[r], zlane);
        const float rz0 = __builtin_amdgcn_rcpf(zr0);
        const float rz1 = __builtin_amdgcn_rcpf(zr1);
        if (lm < 16) {
            ET[mrow * ETS + lm]        = (_Float16)(pv0[r] * rz0);
            ET[(mrow + 32) * ETS + lm] = (_Float16)(pv1[r] * rz1);
        }
    }
    asm volatile("s_waitcnt lgkmcnt(0)" ::: "memory");
    __builtin_amdgcn_sched_barrier(0);

    // Ht[b][hh][m][16], hh = NH-1-n; wave writes 64 rows x 32B contiguous.
    {
        _Float16* Hb2 = Ht + (((size_t)b * NH_ + (NH_ - 1 - n)) * 512 + (m0 + ln)) * 16;
        const h4 e0 = *(const h4*)&ET[ln * ETS + 0];
        const h4 e1 = *(const h4*)&ET[ln * ETS + 4];
        const h4 e2 = *(const h4*)&ET[ln * ETS + 8];
        const h4 e3 = *(const h4*)&ET[ln * ETS + 12];
        *(h4*)&Hb2[0]  = e0;
        *(h4*)&Hb2[4]  = e1;
        *(h4*)&Hb2[8]  = e2;
        *(h4*)&Hb2[12] = e3;
    }

    // ================= grid-wide handoff =================
    __threadfence();                 // device-scope visibility (cross-XCD)
    cg::this_grid().sync();

    // ================= Phase B: out_proj (2 tasks per block) ==============
    {
        const int task = blockIdx.x * 2 + (t >> 8);   // 0..511
        const int tt   = t & 255;
        const int ct   = task & 15;        // col0 = ct*32
        const int b2   = task >> 4;
        const int wv2  = tt >> 6;          // 0..3
        const int ln2  = tt & 63;
        const int l162 = ln2 & 15;
        const int g42  = ln2 >> 4;
        const int col0 = ct * 32;

        const float* Wb = Wo + (size_t)b2 * D_ * D_;
        const _Float16* Hb = Ht + (size_t)b2 * NH_ * 512 * 16;

        f32x4 acc[2][2];
        #pragma unroll
        for (int mt = 0; mt < 2; ++mt)
            #pragma unroll
            for (int nt = 0; nt < 2; ++nt) acc[mt][nt] = (f32x4){0.f,0.f,0.f,0.f};

        #pragma unroll
        for (int ks = 0; ks < 4; ++ks) {
            const int k0 = ks * 32 + g42 * 8;
            const int hh = k0 >> 4;
            const int kr = k0 & 15;
            h8 Ah[2];
            #pragma unroll
            for (int mt = 0; mt < 2; ++mt) {
                const float* ap = Wb + (size_t)(wv2 * 32 + mt * 16 + l162) * D_ + k0;
                const f32x4 w0 = *(const f32x4*)ap, w1 = *(const f32x4*)(ap + 4);
                #pragma unroll
                for (int j = 0; j < 4; ++j) {
                    Ah[mt][j] = (_Float16)w0[j]; Ah[mt][j + 4] = (_Float16)w1[j];
                }
            }
            h8 Bh[2];
            #pragma unroll
            for (int nt = 0; nt < 2; ++nt)
                Bh[nt] = *(const h8*)&Hb[((size_t)hh * 512 + col0 + nt * 16 + l162) * 16 + kr];
            #pragma unroll
            for (int mt = 0; mt < 2; ++mt)
                #pragma unroll
                for (int nt = 0; nt < 2; ++nt)
                    acc[mt][nt] = MFMA_K32(Ah[mt], Bh[nt], acc[mt][nt]);
        }

        float* ob = out + (size_t)b2 * D_ * L_;
        #pragma unroll
        for (int mt = 0; mt < 2; ++mt) {
            #pragma unroll
            for (int nt = 0; nt < 2; ++nt) {
                #pragma unroll
                for (int r = 0; r < 4; ++r) {
                    ob[(size_t)(wv2 * 32 + mt * 16 + g42 * 4 + r) * L_ + col0 + nt * 16 + l162]
                        = acc[mt][nt][r];
                }
            }
        }
    }
}

extern "C" void kernel_launch(void* const* d_in, const int* in_sizes, int n_in,
                              void* d_out, int out_size, void* d_ws, size_t ws_size,
                              hipStream_t stream)
{
    const float* x  = (const float*)d_in[0];
    const float* Wq = (const float*)d_in[1];
    const float* Wk = (const float*)d_in[2];
    const float* Wv = (const float*)d_in[3];
    const float* Wo = (const float*)d_in[4];
    float* out = (float*)d_out;

    _Float16* Ht = (_Float16*)d_ws;                       // 4 MB head-major

    void* args[] = { (void*)&x, (void*)&Wq, (void*)&Wk, (void*)&Wv,
                     (void*)&Wo, (void*)&Ht, (void*)&out };
    hipLaunchCooperativeKernel((void*)attn_fused_coop,
                               dim3(NH_ * B_), dim3(512), args, 0, stream);
}

// Round 22
// 35.004 us; speedup vs baseline: 4.2186x; 4.2186x over previous
//
#include <hip/hip_runtime.h>
#include <hip/hip_bf16.h>
#include <math.h>

#define B_   32
#define D_   128
#define L_   512
#define NH_  8
#define DK_  16

#define QKS  24    // Qh/Kh row stride in f16 ([512][16] + pad 8): 48B rows, 16B-aligned
#define VST  520   // V row stride ([16][512] + pad 8)
#define XST  40    // x-stage row stride ([512][32] + pad 8), XOR-swizzled banks
#define ETS  20    // epilogue tile row stride in f16 ([64][16] + pad 4)

#define LOG2E 1.4426950408889634f
#define QSC   (0.25f * LOG2E)          // fold 1/sqrt(dk) * log2(e) into Q
#define SH2   (-11.541560327111707f)   // -8 * log2(e): softmax shift, in MFMA acc

typedef _Float16 h2 __attribute__((ext_vector_type(2)));
typedef _Float16 h4 __attribute__((ext_vector_type(4)));
typedef _Float16 h8 __attribute__((ext_vector_type(8)));
typedef __attribute__((ext_vector_type(4)))  float f32x4;
typedef __attribute__((ext_vector_type(16))) float f32x16;
typedef unsigned int u32x2 __attribute__((ext_vector_type(2)));
typedef unsigned int u32x4 __attribute__((ext_vector_type(4)));

__device__ __forceinline__ unsigned int cvt_pk_u(float a, float b) {
    return __builtin_bit_cast(unsigned int, __builtin_amdgcn_cvt_pkrtz(a, b));
}

#define MFMA_K32(a, b, c) __builtin_amdgcn_mfma_f32_16x16x32_f16((a), (b), (c), 0, 0, 0)
#define MFMA_32(a, b, c)  __builtin_amdgcn_mfma_f32_32x32x16_f16((a), (b), (c), 0, 0, 0)

// ---------------------------------------------------------------------------
// Kernel A: fused attention (R20 champion + T5 s_setprio around P2 MFMA
// clusters). 512 thr = 8 waves, bounds (512,2).
// ---------------------------------------------------------------------------
__global__ __launch_bounds__(512, 2) void attn_mfma(
    const float* __restrict__ x,      // [B][D][L] fp32
    const float* __restrict__ Wq,     // [NH][B][DK][D]
    const float* __restrict__ Wk,
    const float* __restrict__ Wv,
    _Float16* __restrict__ Ht)        // [B][8][512][16] fp16 head-major
{
    __shared__ __attribute__((aligned(16))) unsigned char SMEM[2 * 512 * XST * 2]; // 80 KB
    __shared__ __attribute__((aligned(16))) _Float16 Qh[512 * QKS];   // 24.6 KB
    __shared__ __attribute__((aligned(16))) _Float16 Kh[512 * QKS];   // 24.6 KB
    __shared__ __attribute__((aligned(16))) _Float16 Vs[16 * VST];    // 16.6 KB

    _Float16* T32a = (_Float16*)SMEM;
    _Float16* T32b = T32a + 512 * XST;

    const int nb = blockIdx.x;
    const int n  = nb >> 5;
    const int b  = nb & 31;
    const int t  = threadIdx.x;
    const int wv = t >> 6;          // wave 0..7
    const int ln = t & 63;
    const int l16 = ln & 15;
    const int g4  = ln >> 4;        // 0..3
    const int lm  = ln & 31;        // 32-tile row/col index
    const int hi  = ln >> 5;        // 0..1

    const float* xb = x + (size_t)b * D_ * L_;
    const size_t woff = (size_t)(n * B_ + b) * DK_ * D_;
    const float* pWq = Wq + woff;
    const float* pWk = Wk + woff;
    const float* pWv = Wv + woff;

    // staging assignment: thread t handles d-octet sdd, l-quad sl0
    const int sdd  = (t >> 7) * 8;         // 0,8,16,24 (local d base)
    const int sl0  = (t & 127) * 4;        // l base 0..508
    const int sxor = ((t & 127) & 3) << 3; // bank swizzle

    #define STAGE(ks_, buf_)                                                   \
    {                                                                          \
        f32x4 xv[8];                                                           \
        _Pragma("unroll")                                                      \
        for (int j = 0; j < 8; ++j)                                            \
            xv[j] = *(const f32x4*)&xb[(size_t)((ks_) * 32 + sdd + j) * L_ + sl0]; \
        _Pragma("unroll")                                                      \
        for (int i = 0; i < 4; ++i) {                                          \
            h8 w;                                                              \
            _Pragma("unroll")                                                  \
            for (int j = 0; j < 8; ++j) w[j] = (_Float16)xv[j][i];             \
            *(h8*)&(buf_)[(sl0 + i) * XST + (sdd ^ sxor)] = w;                 \
        }                                                                      \
    }

    // ================= P1: Q,K,V = W @ x  (fp16 16x16x32 MFMA) ============
    f32x4 Qa[4], Ka[4], Va[4];
    #pragma unroll
    for (int lt = 0; lt < 4; ++lt) {
        Qa[lt] = (f32x4){0.f,0.f,0.f,0.f};
        Ka[lt] = (f32x4){0.f,0.f,0.f,0.f};
        Va[lt] = (f32x4){0.f,0.f,0.f,0.f};
    }

    STAGE(0, T32a);
    __syncthreads();

    #pragma unroll
    for (int ks = 0; ks < 4; ++ks) {
        _Float16* cur = (ks & 1) ? T32b : T32a;
        _Float16* nxt = (ks & 1) ? T32a : T32b;
        if (ks < 3) STAGE(ks + 1, nxt);     // loads issue before compute(ks)

        const int d0 = ks * 32 + g4 * 8;    // A/B-frag k = 8*g4 + j
        const float* aq = pWq + l16 * D_ + d0;
        const float* ak = pWk + l16 * D_ + d0;
        const float* av = pWv + l16 * D_ + d0;
        const f32x4 q0 = *(const f32x4*)aq, q1 = *(const f32x4*)(aq + 4);
        const f32x4 k0 = *(const f32x4*)ak, k1 = *(const f32x4*)(ak + 4);
        const f32x4 v0 = *(const f32x4*)av, v1 = *(const f32x4*)(av + 4);
        h8 Aq, Ak, Av;
        #pragma unroll
        for (int j = 0; j < 4; ++j) {
            Aq[j] = (_Float16)q0[j]; Aq[j + 4] = (_Float16)q1[j];
            Ak[j] = (_Float16)k0[j]; Ak[j + 4] = (_Float16)k1[j];
            Av[j] = (_Float16)v0[j]; Av[j + 4] = (_Float16)v1[j];
        }
        #pragma unroll
        for (int lt = 0; lt < 4; ++lt) {
            const int l = wv * 64 + lt * 16 + l16;
            const h8 Bx = *(const h8*)&cur[l * XST + ((g4 * 8) ^ ((((l) >> 2) & 3) << 3))];
            Qa[lt] = MFMA_K32(Aq, Bx, Qa[lt]);
            Ka[lt] = MFMA_K32(Ak, Bx, Ka[lt]);
            Va[lt] = MFMA_K32(Av, Bx, Va[lt]);
        }
        __syncthreads();
    }

    // Q^T (pre-scaled by 0.25*log2e), K^T, V -> LDS.
    #pragma unroll
    for (int lt = 0; lt < 4; ++lt) {
        const int l = wv * 64 + lt * 16 + l16;
        h4 qv, kv;
        #pragma unroll
        for (int r = 0; r < 4; ++r) {
            qv[r] = (_Float16)(Qa[lt][r] * QSC);
            kv[r] = (_Float16)Ka[lt][r];
            Vs[(g4 * 4 + r) * VST + l] = (_Float16)Va[lt][r];
        }
        *(h4*)&Qh[l * QKS + g4 * 4] = qv;
        *(h4*)&Kh[l * QKS + g4 * 4] = kv;
    }
    __syncthreads();   // after this, T32a/b are dead -> reusable by epilogue

    // ====== P2: 2 x 32-m-tiles per wave, shared B-side reads, free Z ======
    const int m0 = wv * 64;
    const h8 Bk0 = *(const h8*)&Kh[(m0 + lm) * QKS + 8 * hi];
    const h8 Bk1 = *(const h8*)&Kh[(m0 + 32 + lm) * QKS + 8 * hi];

    f32x16 shiftacc, pv0, pv1;
    #pragma unroll
    for (int i = 0; i < 16; ++i) { shiftacc[i] = SH2; pv0[i] = 0.f; pv1[i] = 0.f; }

    const bool vsel = (lm < 16);
    const int  vrow = lm & 15;
    const h8 ones8 = {(_Float16)1.f,(_Float16)1.f,(_Float16)1.f,(_Float16)1.f,
                      (_Float16)1.f,(_Float16)1.f,(_Float16)1.f,(_Float16)1.f};

    #pragma unroll 2
    for (int t32 = 0; t32 < 16; ++t32) {
        const int lb = t32 * 32;
        const h8 Aq2  = *(const h8*)&Qh[(lb + lm) * QKS + 8 * hi];
        const h8 Bv1r = *(const h8*)&Vs[vrow * VST + lb + 8 * hi];
        const h8 Bv2r = *(const h8*)&Vs[vrow * VST + lb + 16 + 8 * hi];
        const h8 Bv1 = vsel ? Bv1r : ones8;
        const h8 Bv2 = vsel ? Bv2r : ones8;

        __builtin_amdgcn_s_setprio(1);
        const f32x16 sc0 = MFMA_32(Aq2, Bk0, shiftacc);  // pre-shifted scores
        const f32x16 sc1 = MFMA_32(Aq2, Bk1, shiftacc);
        __builtin_amdgcn_s_setprio(0);

        float pA[16], pB[16];
        #pragma unroll
        for (int r = 0; r < 16; ++r) pA[r] = __builtin_amdgcn_exp2f(sc0[r]);
        #pragma unroll
        for (int r = 0; r < 16; ++r) pB[r] = __builtin_amdgcn_exp2f(sc1[r]);

        const unsigned int a0 = cvt_pk_u(pA[0],  pA[1]);
        const unsigned int a1 = cvt_pk_u(pA[2],  pA[3]);
        const unsigned int a2 = cvt_pk_u(pA[4],  pA[5]);
        const unsigned int a3 = cvt_pk_u(pA[6],  pA[7]);
        const unsigned int a4 = cvt_pk_u(pA[8],  pA[9]);
        const unsigned int a5 = cvt_pk_u(pA[10], pA[11]);
        const unsigned int a6 = cvt_pk_u(pA[12], pA[13]);
        const unsigned int a7 = cvt_pk_u(pA[14], pA[15]);
        const unsigned int b0 = cvt_pk_u(pB[0],  pB[1]);
        const unsigned int b1 = cvt_pk_u(pB[2],  pB[3]);
        const unsigned int b2 = cvt_pk_u(pB[4],  pB[5]);
        const unsigned int b3 = cvt_pk_u(pB[6],  pB[7]);
        const unsigned int b4 = cvt_pk_u(pB[8],  pB[9]);
        const unsigned int b5 = cvt_pk_u(pB[10], pB[11]);
        const unsigned int b6 = cvt_pk_u(pB[12], pB[13]);
        const unsigned int b7 = cvt_pk_u(pB[14], pB[15]);

        const u32x2 sA02 = __builtin_amdgcn_permlane32_swap(a0, a2, false, false);
        const u32x2 sA13 = __builtin_amdgcn_permlane32_swap(a1, a3, false, false);
        const u32x2 sA46 = __builtin_amdgcn_permlane32_swap(a4, a6, false, false);
        const u32x2 sA57 = __builtin_amdgcn_permlane32_swap(a5, a7, false, false);
        const u32x2 sB02 = __builtin_amdgcn_permlane32_swap(b0, b2, false, false);
        const u32x2 sB13 = __builtin_amdgcn_permlane32_swap(b1, b3, false, false);
        const u32x2 sB46 = __builtin_amdgcn_permlane32_swap(b4, b6, false, false);
        const u32x2 sB57 = __builtin_amdgcn_permlane32_swap(b5, b7, false, false);
        const h8 A1m0 = __builtin_bit_cast(h8, (u32x4){sA02.x, sA13.x, sA02.y, sA13.y});
        const h8 A2m0 = __builtin_bit_cast(h8, (u32x4){sA46.x, sA57.x, sA46.y, sA57.y});
        const h8 A1m1 = __builtin_bit_cast(h8, (u32x4){sB02.x, sB13.x, sB02.y, sB13.y});
        const h8 A2m1 = __builtin_bit_cast(h8, (u32x4){sB46.x, sB57.x, sB46.y, sB57.y});

        __builtin_amdgcn_s_setprio(1);
        pv0 = MFMA_32(A1m0, Bv1, pv0);
        pv0 = MFMA_32(A2m0, Bv2, pv0);
        pv1 = MFMA_32(A1m1, Bv1, pv1);
        pv1 = MFMA_32(A2m1, Bv2, pv1);
        __builtin_amdgcn_s_setprio(0);
    }

    // ====== epilogue: normalize -> per-wave LDS tile -> coalesced store ===
    _Float16* ET = ((_Float16*)SMEM) + wv * 64 * ETS;
    const int zlane = 16 + 32 * hi;
    #pragma unroll
    for (int r = 0; r < 16; ++r) {
        const int mrow = (r & 3) + 8 * (r >> 2) + 4 * hi;
        const float zr0 = __shfl(pv0[r], zlane);
        const float zr1 = __shfl(pv1[r], zlane);
        const float rz0 = __builtin_amdgcn_rcpf(zr0);
        const float rz1 = __builtin_amdgcn_rcpf(zr1);
        if (lm < 16) {
            ET[mrow * ETS + lm]        = (_Float16)(pv0[r] * rz0);
            ET[(mrow + 32) * ETS + lm] = (_Float16)(pv1[r] * rz1);
        }
    }
    // in-wave LDS write->read fence (rule #18: waitcnt + sched_barrier)
    asm volatile("s_waitcnt lgkmcnt(0)" ::: "memory");
    __builtin_amdgcn_sched_barrier(0);

    // Ht[b][hh][m][16], hh = NH-1-n; wave writes 64 rows x 32B contiguous.
    _Float16* Hb2 = Ht + (((size_t)b * NH_ + (NH_ - 1 - n)) * 512 + (m0 + ln)) * 16;
    const h4 e0 = *(const h4*)&ET[ln * ETS + 0];
    const h4 e1 = *(const h4*)&ET[ln * ETS + 4];
    const h4 e2 = *(const h4*)&ET[ln * ETS + 8];
    const h4 e3 = *(const h4*)&ET[ln * ETS + 12];
    *(h4*)&Hb2[0]  = e0;
    *(h4*)&Hb2[4]  = e1;
    *(h4*)&Hb2[8]  = e2;
    *(h4*)&Hb2[12] = e3;
}

// ---------------------------------------------------------------------------
// Kernel B: out[b] = Wo[b] (128x128) @ heads[b] (128x512), fp16 MFMA,
// pure-register. grid (16 col-tiles, 32 b) = 512 blocks x 256 thr
// -> 2 independent blocks/CU. Ht is head-major: B[k][col] =
// Ht[b][k>>4][col][k&15] (single aligned h8 load per frag).
// ---------------------------------------------------------------------------
__global__ __launch_bounds__(256, 2) void out_proj_mfma(
    const float* __restrict__ Wo,        // [B][128][128]
    const _Float16* __restrict__ Ht,     // [B][8][512][16]
    float* __restrict__ out)             // [B][128][512]
{
    const int ct = blockIdx.x;     // col0 = ct*32
    const int b  = blockIdx.y;
    const int t  = threadIdx.x;
    const int wv = t >> 6;         // 0..3
    const int ln = t & 63;
    const int l16 = ln & 15;
    const int g4  = ln >> 4;
    const int col0 = ct * 32;

    const float* Wb = Wo + (size_t)b * D_ * D_;
    const _Float16* Hb = Ht + (size_t)b * NH_ * 512 * 16;

    f32x4 acc[2][2];
    #pragma unroll
    for (int mt = 0; mt < 2; ++mt)
        #pragma unroll
        for (int nt = 0; nt < 2; ++nt) acc[mt][nt] = (f32x4){0.f,0.f,0.f,0.f};

    #pragma unroll
    for (int ks = 0; ks < 4; ++ks) {
        const int k0 = ks * 32 + g4 * 8;
        const int hh = k0 >> 4;            // head slice
        const int kr = k0 & 15;            // offset within head (0 or 8)
        h8 Ah[2];
        #pragma unroll
        for (int mt = 0; mt < 2; ++mt) {
            const float* ap = Wb + (size_t)(wv * 32 + mt * 16 + l16) * D_ + k0;
            const f32x4 w0 = *(const f32x4*)ap, w1 = *(const f32x4*)(ap + 4);
            #pragma unroll
            for (int j = 0; j < 4; ++j) {
                Ah[mt][j] = (_Float16)w0[j]; Ah[mt][j + 4] = (_Float16)w1[j];
            }
        }
        h8 Bh[2];
        #pragma unroll
        for (int nt = 0; nt < 2; ++nt)
            Bh[nt] = *(const h8*)&Hb[((size_t)hh * 512 + col0 + nt * 16 + l16) * 16 + kr];
        #pragma unroll
        for (int mt = 0; mt < 2; ++mt)
            #pragma unroll
            for (int nt = 0; nt < 2; ++nt)
                acc[mt][nt] = MFMA_K32(Ah[mt], Bh[nt], acc[mt][nt]);
    }

    float* ob = out + (size_t)b * D_ * L_;
    #pragma unroll
    for (int mt = 0; mt < 2; ++mt) {
        #pragma unroll
        for (int nt = 0; nt < 2; ++nt) {
            #pragma unroll
            for (int r = 0; r < 4; ++r) {
                ob[(size_t)(wv * 32 + mt * 16 + g4 * 4 + r) * L_ + col0 + nt * 16 + l16]
                    = acc[mt][nt][r];
            }
        }
    }
}

extern "C" void kernel_launch(void* const* d_in, const int* in_sizes, int n_in,
                              void* d_out, int out_size, void* d_ws, size_t ws_size,
                              hipStream_t stream)
{
    const float* x  = (const float*)d_in[0];
    const float* Wq = (const float*)d_in[1];
    const float* Wk = (const float*)d_in[2];
    const float* Wv = (const float*)d_in[3];
    const float* Wo = (const float*)d_in[4];
    float* out = (float*)d_out;

    _Float16* Ht = (_Float16*)d_ws;                       // 4 MB head-major

    attn_mfma<<<dim3(NH_ * B_), dim3(512), 0, stream>>>(x, Wq, Wk, Wv, Ht);
    out_proj_mfma<<<dim3(16, B_), dim3(256), 0, stream>>>(Wo, Ht, out);
}

// Round 23
// 34.127 us; speedup vs baseline: 4.3270x; 1.0257x over previous
//
#include <hip/hip_runtime.h>
#include <hip/hip_bf16.h>
#include <math.h>

#define B_   32
#define D_   128
#define L_   512
#define NH_  8
#define DK_  16

#define QKS  24    // Qh/Kh row stride in f16 ([512][16] + pad 8): 48B rows, 16B-aligned
#define VST  520   // V row stride ([16][512] + pad 8)
#define XST  40    // x-stage row stride ([512][32] + pad 8), XOR-swizzled banks
#define ETS  20    // epilogue tile row stride in f16 ([64][16] + pad 4)

#define LOG2E 1.4426950408889634f
#define QSC   (0.25f * LOG2E)          // fold 1/sqrt(dk) * log2(e) into Q
#define SH2   (-11.541560327111707f)   // -8 * log2(e): softmax shift, in MFMA acc

typedef _Float16 h2 __attribute__((ext_vector_type(2)));
typedef _Float16 h4 __attribute__((ext_vector_type(4)));
typedef _Float16 h8 __attribute__((ext_vector_type(8)));
typedef __attribute__((ext_vector_type(4)))  float f32x4;
typedef __attribute__((ext_vector_type(16))) float f32x16;
typedef unsigned int u32x2 __attribute__((ext_vector_type(2)));
typedef unsigned int u32x4 __attribute__((ext_vector_type(4)));

__device__ __forceinline__ unsigned int cvt_pk_u(float a, float b) {
    return __builtin_bit_cast(unsigned int, __builtin_amdgcn_cvt_pkrtz(a, b));
}

#define MFMA_K32(a, b, c) __builtin_amdgcn_mfma_f32_16x16x32_f16((a), (b), (c), 0, 0, 0)
#define MFMA_32(a, b, c)  __builtin_amdgcn_mfma_f32_32x32x16_f16((a), (b), (c), 0, 0, 0)

// ---------------------------------------------------------------------------
// Kernel A: fused attention (R20 champion). 512 thr = 8 waves, bounds (512,2).
// In-kernel x transpose (double-buffered, bank-swizzled staging), all-fp16
// MFMA P1, P2 = 2 x 32-m-tiles/wave with shift-in-accumulator softmax, raw
// v_exp_f32, permlane32_swap P->A-frag, free-Z via cndmask ones B-frags,
// coalesced head-major epilogue via per-wave LDS tile.
// Ht layout: [b][hh][m][16] fp16, hh = NH-1-n (head-reversed).
// ---------------------------------------------------------------------------
__global__ __launch_bounds__(512, 2) void attn_mfma(
    const float* __restrict__ x,      // [B][D][L] fp32
    const float* __restrict__ Wq,     // [NH][B][DK][D]
    const float* __restrict__ Wk,
    const float* __restrict__ Wv,
    _Float16* __restrict__ Ht)        // [B][8][512][16] fp16 head-major
{
    __shared__ __attribute__((aligned(16))) unsigned char SMEM[2 * 512 * XST * 2]; // 80 KB
    __shared__ __attribute__((aligned(16))) _Float16 Qh[512 * QKS];   // 24.6 KB
    __shared__ __attribute__((aligned(16))) _Float16 Kh[512 * QKS];   // 24.6 KB
    __shared__ __attribute__((aligned(16))) _Float16 Vs[16 * VST];    // 16.6 KB

    _Float16* T32a = (_Float16*)SMEM;
    _Float16* T32b = T32a + 512 * XST;

    const int nb = blockIdx.x;
    const int n  = nb >> 5;
    const int b  = nb & 31;
    const int t  = threadIdx.x;
    const int wv = t >> 6;          // wave 0..7
    const int ln = t & 63;
    const int l16 = ln & 15;
    const int g4  = ln >> 4;        // 0..3
    const int lm  = ln & 31;        // 32-tile row/col index
    const int hi  = ln >> 5;        // 0..1

    const float* xb = x + (size_t)b * D_ * L_;
    const size_t woff = (size_t)(n * B_ + b) * DK_ * D_;
    const float* pWq = Wq + woff;
    const float* pWk = Wk + woff;
    const float* pWv = Wv + woff;

    // staging assignment: thread t handles d-octet sdd, l-quad sl0
    const int sdd  = (t >> 7) * 8;         // 0,8,16,24 (local d base)
    const int sl0  = (t & 127) * 4;        // l base 0..508
    const int sxor = ((t & 127) & 3) << 3; // bank swizzle: XOR bits 3-4 of half-off

    // stage x-tile ks: [32 d][512 l] fp32 -> buf[l][d^swz] fp16
    #define STAGE(ks_, buf_)                                                   \
    {                                                                          \
        f32x4 xv[8];                                                           \
        _Pragma("unroll")                                                      \
        for (int j = 0; j < 8; ++j)                                            \
            xv[j] = *(const f32x4*)&xb[(size_t)((ks_) * 32 + sdd + j) * L_ + sl0]; \
        _Pragma("unroll")                                                      \
        for (int i = 0; i < 4; ++i) {                                          \
            h8 w;                                                              \
            _Pragma("unroll")                                                  \
            for (int j = 0; j < 8; ++j) w[j] = (_Float16)xv[j][i];             \
            *(h8*)&(buf_)[(sl0 + i) * XST + (sdd ^ sxor)] = w;                 \
        }                                                                      \
    }

    // ================= P1: Q,K,V = W @ x  (fp16 16x16x32 MFMA) ============
    f32x4 Qa[4], Ka[4], Va[4];
    #pragma unroll
    for (int lt = 0; lt < 4; ++lt) {
        Qa[lt] = (f32x4){0.f,0.f,0.f,0.f};
        Ka[lt] = (f32x4){0.f,0.f,0.f,0.f};
        Va[lt] = (f32x4){0.f,0.f,0.f,0.f};
    }

    STAGE(0, T32a);
    __syncthreads();

    #pragma unroll
    for (int ks = 0; ks < 4; ++ks) {
        _Float16* cur = (ks & 1) ? T32b : T32a;
        _Float16* nxt = (ks & 1) ? T32a : T32b;
        if (ks < 3) STAGE(ks + 1, nxt);     // loads issue before compute(ks)

        const int d0 = ks * 32 + g4 * 8;    // A/B-frag k = 8*g4 + j
        const float* aq = pWq + l16 * D_ + d0;
        const float* ak = pWk + l16 * D_ + d0;
        const float* av = pWv + l16 * D_ + d0;
        const f32x4 q0 = *(const f32x4*)aq, q1 = *(const f32x4*)(aq + 4);
        const f32x4 k0 = *(const f32x4*)ak, k1 = *(const f32x4*)(ak + 4);
        const f32x4 v0 = *(const f32x4*)av, v1 = *(const f32x4*)(av + 4);
        h8 Aq, Ak, Av;
        #pragma unroll
        for (int j = 0; j < 4; ++j) {
            Aq[j] = (_Float16)q0[j]; Aq[j + 4] = (_Float16)q1[j];
            Ak[j] = (_Float16)k0[j]; Ak[j + 4] = (_Float16)k1[j];
            Av[j] = (_Float16)v0[j]; Av[j + 4] = (_Float16)v1[j];
        }
        #pragma unroll
        for (int lt = 0; lt < 4; ++lt) {
            const int l = wv * 64 + lt * 16 + l16;
            const h8 Bx = *(const h8*)&cur[l * XST + ((g4 * 8) ^ ((((l) >> 2) & 3) << 3))];
            Qa[lt] = MFMA_K32(Aq, Bx, Qa[lt]);
            Ka[lt] = MFMA_K32(Ak, Bx, Ka[lt]);
            Va[lt] = MFMA_K32(Av, Bx, Va[lt]);
        }
        __syncthreads();
    }

    // Q^T (pre-scaled by 0.25*log2e), K^T, V -> LDS.
    #pragma unroll
    for (int lt = 0; lt < 4; ++lt) {
        const int l = wv * 64 + lt * 16 + l16;
        h4 qv, kv;
        #pragma unroll
        for (int r = 0; r < 4; ++r) {
            qv[r] = (_Float16)(Qa[lt][r] * QSC);
            kv[r] = (_Float16)Ka[lt][r];
            Vs[(g4 * 4 + r) * VST + l] = (_Float16)Va[lt][r];
        }
        *(h4*)&Qh[l * QKS + g4 * 4] = qv;
        *(h4*)&Kh[l * QKS + g4 * 4] = kv;
    }
    __syncthreads();   // after this, T32a/b are dead -> reusable by epilogue

    // ====== P2: 2 x 32-m-tiles per wave, shared B-side reads, free Z ======
    const int m0 = wv * 64;
    const h8 Bk0 = *(const h8*)&Kh[(m0 + lm) * QKS + 8 * hi];
    const h8 Bk1 = *(const h8*)&Kh[(m0 + 32 + lm) * QKS + 8 * hi];

    f32x16 shiftacc, pv0, pv1;
    #pragma unroll
    for (int i = 0; i < 16; ++i) { shiftacc[i] = SH2; pv0[i] = 0.f; pv1[i] = 0.f; }

    const bool vsel = (lm < 16);
    const int  vrow = lm & 15;
    const h8 ones8 = {(_Float16)1.f,(_Float16)1.f,(_Float16)1.f,(_Float16)1.f,
                      (_Float16)1.f,(_Float16)1.f,(_Float16)1.f,(_Float16)1.f};

    #pragma unroll 2
    for (int t32 = 0; t32 < 16; ++t32) {
        const int lb = t32 * 32;
        const h8 Aq2  = *(const h8*)&Qh[(lb + lm) * QKS + 8 * hi];
        const h8 Bv1r = *(const h8*)&Vs[vrow * VST + lb + 8 * hi];
        const h8 Bv2r = *(const h8*)&Vs[vrow * VST + lb + 16 + 8 * hi];
        const h8 Bv1 = vsel ? Bv1r : ones8;
        const h8 Bv2 = vsel ? Bv2r : ones8;

        const f32x16 sc0 = MFMA_32(Aq2, Bk0, shiftacc);  // pre-shifted scores
        const f32x16 sc1 = MFMA_32(Aq2, Bk1, shiftacc);

        float pA[16], pB[16];
        #pragma unroll
        for (int r = 0; r < 16; ++r) pA[r] = __builtin_amdgcn_exp2f(sc0[r]);
        #pragma unroll
        for (int r = 0; r < 16; ++r) pB[r] = __builtin_amdgcn_exp2f(sc1[r]);

        const unsigned int a0 = cvt_pk_u(pA[0],  pA[1]);
        const unsigned int a1 = cvt_pk_u(pA[2],  pA[3]);
        const unsigned int a2 = cvt_pk_u(pA[4],  pA[5]);
        const unsigned int a3 = cvt_pk_u(pA[6],  pA[7]);
        const unsigned int a4 = cvt_pk_u(pA[8],  pA[9]);
        const unsigned int a5 = cvt_pk_u(pA[10], pA[11]);
        const unsigned int a6 = cvt_pk_u(pA[12], pA[13]);
        const unsigned int a7 = cvt_pk_u(pA[14], pA[15]);
        const unsigned int b0 = cvt_pk_u(pB[0],  pB[1]);
        const unsigned int b1 = cvt_pk_u(pB[2],  pB[3]);
        const unsigned int b2 = cvt_pk_u(pB[4],  pB[5]);
        const unsigned int b3 = cvt_pk_u(pB[6],  pB[7]);
        const unsigned int b4 = cvt_pk_u(pB[8],  pB[9]);
        const unsigned int b5 = cvt_pk_u(pB[10], pB[11]);
        const unsigned int b6 = cvt_pk_u(pB[12], pB[13]);
        const unsigned int b7 = cvt_pk_u(pB[14], pB[15]);

        const u32x2 sA02 = __builtin_amdgcn_permlane32_swap(a0, a2, false, false);
        const u32x2 sA13 = __builtin_amdgcn_permlane32_swap(a1, a3, false, false);
        const u32x2 sA46 = __builtin_amdgcn_permlane32_swap(a4, a6, false, false);
        const u32x2 sA57 = __builtin_amdgcn_permlane32_swap(a5, a7, false, false);
        const u32x2 sB02 = __builtin_amdgcn_permlane32_swap(b0, b2, false, false);
        const u32x2 sB13 = __builtin_amdgcn_permlane32_swap(b1, b3, false, false);
        const u32x2 sB46 = __builtin_amdgcn_permlane32_swap(b4, b6, false, false);
        const u32x2 sB57 = __builtin_amdgcn_permlane32_swap(b5, b7, false, false);
        const h8 A1m0 = __builtin_bit_cast(h8, (u32x4){sA02.x, sA13.x, sA02.y, sA13.y});
        const h8 A2m0 = __builtin_bit_cast(h8, (u32x4){sA46.x, sA57.x, sA46.y, sA57.y});
        const h8 A1m1 = __builtin_bit_cast(h8, (u32x4){sB02.x, sB13.x, sB02.y, sB13.y});
        const h8 A2m1 = __builtin_bit_cast(h8, (u32x4){sB46.x, sB57.x, sB46.y, sB57.y});

        pv0 = MFMA_32(A1m0, Bv1, pv0);
        pv0 = MFMA_32(A2m0, Bv2, pv0);
        pv1 = MFMA_32(A1m1, Bv1, pv1);
        pv1 = MFMA_32(A2m1, Bv2, pv1);
    }

    // ====== epilogue: normalize -> per-wave LDS tile -> coalesced store ===
    _Float16* ET = ((_Float16*)SMEM) + wv * 64 * ETS;
    const int zlane = 16 + 32 * hi;
    #pragma unroll
    for (int r = 0; r < 16; ++r) {
        const int mrow = (r & 3) + 8 * (r >> 2) + 4 * hi;
        const float zr0 = __shfl(pv0[r], zlane);
        const float zr1 = __shfl(pv1[r], zlane);
        const float rz0 = __builtin_amdgcn_rcpf(zr0);
        const float rz1 = __builtin_amdgcn_rcpf(zr1);
        if (lm < 16) {
            ET[mrow * ETS + lm]        = (_Float16)(pv0[r] * rz0);
            ET[(mrow + 32) * ETS + lm] = (_Float16)(pv1[r] * rz1);
        }
    }
    // in-wave LDS write->read fence (rule #18: waitcnt + sched_barrier)
    asm volatile("s_waitcnt lgkmcnt(0)" ::: "memory");
    __builtin_amdgcn_sched_barrier(0);

    // Ht[b][hh][m][16], hh = NH-1-n; wave writes 64 rows x 32B contiguous.
    _Float16* Hb2 = Ht + (((size_t)b * NH_ + (NH_ - 1 - n)) * 512 + (m0 + ln)) * 16;
    const h4 e0 = *(const h4*)&ET[ln * ETS + 0];
    const h4 e1 = *(const h4*)&ET[ln * ETS + 4];
    const h4 e2 = *(const h4*)&ET[ln * ETS + 8];
    const h4 e3 = *(const h4*)&ET[ln * ETS + 12];
    *(h4*)&Hb2[0]  = e0;
    *(h4*)&Hb2[4]  = e1;
    *(h4*)&Hb2[8]  = e2;
    *(h4*)&Hb2[12] = e3;
}

// ---------------------------------------------------------------------------
// Kernel B: out[b] = Wo[b] (128x128) @ heads[b] (128x512), fp16 MFMA,
// pure-register. grid (16 col-tiles, 32 b) = 512 blocks x 256 thr
// -> 2 independent blocks/CU. Ht is head-major: B[k][col] =
// Ht[b][k>>4][col][k&15] (single aligned h8 load per frag).
// ---------------------------------------------------------------------------
__global__ __launch_bounds__(256, 2) void out_proj_mfma(
    const float* __restrict__ Wo,        // [B][128][128]
    const _Float16* __restrict__ Ht,     // [B][8][512][16]
    float* __restrict__ out)             // [B][128][512]
{
    const int ct = blockIdx.x;     // col0 = ct*32
    const int b  = blockIdx.y;
    const int t  = threadIdx.x;
    const int wv = t >> 6;         // 0..3
    const int ln = t & 63;
    const int l16 = ln & 15;
    const int g4  = ln >> 4;
    const int col0 = ct * 32;

    const float* Wb = Wo + (size_t)b * D_ * D_;
    const _Float16* Hb = Ht + (size_t)b * NH_ * 512 * 16;

    f32x4 acc[2][2];
    #pragma unroll
    for (int mt = 0; mt < 2; ++mt)
        #pragma unroll
        for (int nt = 0; nt < 2; ++nt) acc[mt][nt] = (f32x4){0.f,0.f,0.f,0.f};

    #pragma unroll
    for (int ks = 0; ks < 4; ++ks) {
        const int k0 = ks * 32 + g4 * 8;
        const int hh = k0 >> 4;            // head slice
        const int kr = k0 & 15;            // offset within head (0 or 8)
        h8 Ah[2];
        #pragma unroll
        for (int mt = 0; mt < 2; ++mt) {
            const float* ap = Wb + (size_t)(wv * 32 + mt * 16 + l16) * D_ + k0;
            const f32x4 w0 = *(const f32x4*)ap, w1 = *(const f32x4*)(ap + 4);
            #pragma unroll
            for (int j = 0; j < 4; ++j) {
                Ah[mt][j] = (_Float16)w0[j]; Ah[mt][j + 4] = (_Float16)w1[j];
            }
        }
        h8 Bh[2];
        #pragma unroll
        for (int nt = 0; nt < 2; ++nt)
            Bh[nt] = *(const h8*)&Hb[((size_t)hh * 512 + col0 + nt * 16 + l16) * 16 + kr];
        #pragma unroll
        for (int mt = 0; mt < 2; ++mt)
            #pragma unroll
            for (int nt = 0; nt < 2; ++nt)
                acc[mt][nt] = MFMA_K32(Ah[mt], Bh[nt], acc[mt][nt]);
    }

    float* ob = out + (size_t)b * D_ * L_;
    #pragma unroll
    for (int mt = 0; mt < 2; ++mt) {
        #pragma unroll
        for (int nt = 0; nt < 2; ++nt) {
            #pragma unroll
            for (int r = 0; r < 4; ++r) {
                ob[(size_t)(wv * 32 + mt * 16 + g4 * 4 + r) * L_ + col0 + nt * 16 + l16]
                    = acc[mt][nt][r];
            }
        }
    }
}

extern "C" void kernel_launch(void* const* d_in, const int* in_sizes, int n_in,
                              void* d_out, int out_size, void* d_ws, size_t ws_size,
                              hipStream_t stream)
{
    const float* x  = (const float*)d_in[0];
    const float* Wq = (const float*)d_in[1];
    const float* Wk = (const float*)d_in[2];
    const float* Wv = (const float*)d_in[3];
    const float* Wo = (const float*)d_in[4];
    float* out = (float*)d_out;

    _Float16* Ht = (_Float16*)d_ws;                       // 4 MB head-major

    attn_mfma<<<dim3(NH_ * B_), dim3(512), 0, stream>>>(x, Wq, Wk, Wv, Ht);
    out_proj_mfma<<<dim3(16, B_), dim3(256), 0, stream>>>(Wo, Ht, out);
}